// Round 1
// baseline (3316.816 us; speedup 1.0000x reference)
//
#include <hip/hip_runtime.h>
#include <hip/hip_bf16.h>
#include <math.h>

#define E 16
#define B 1024
#define F 16
#define HC 1280
#define DX 1025
#define MH 256

#define TM 64
#define TN 64
#define TK 16

#define LOG2PI 1.8378770664093453f

// ---------------------------------------------------------------------------
// MADE masks, computed analytically.
// degh[j] = j % 15.  order[i] = i (k even) or 15-i (k odd).
// M1 (272x256): rows 0..15 have deg order[i], rows 16.. have deg -1 (always on)
// M2 (256x256): (j%15) >= (i%15)
// M3 (256x32):  degout[n]=order[n&15];  degout[n] > (i%15)
// ---------------------------------------------------------------------------
__device__ __forceinline__ float made_mask(int mode, int rev, int kg, int n) {
    if (mode == 1) {
        if (kg < 16) {
            int din = rev ? (15 - kg) : kg;
            return ((n % 15) >= din) ? 1.f : 0.f;
        }
        return 1.f;
    } else if (mode == 2) {
        return ((n % 15) >= (kg % 15)) ? 1.f : 0.f;
    } else {
        int dout = rev ? (15 - (n & 15)) : (n & 15);
        return (dout > (kg % 15)) ? 1.f : 0.f;
    }
}

// ---------------------------------------------------------------------------
// prep: per-row time-bin index -> per-expert row lists
// BINS match np.linspace in float64, cast to float32 (exactly reproduced).
// ---------------------------------------------------------------------------
__global__ __launch_bounds__(1024) void prep_kernel(const float* __restrict__ t,
                                                    int* __restrict__ rowlist,
                                                    int* __restrict__ counts) {
    __shared__ int sc[E];
    int b = threadIdx.x;
    if (b < E) sc[b] = 0;
    __syncthreads();
    float tv = t[b];
    int idx = 0;
#pragma unroll
    for (int i = 1; i <= 15; ++i) {
        double v;
        if (i < 7)       v = (double)i * (1.5 / 7.0);
        else if (i < 13) v = 1.5 + (double)(i - 7) * (3.5 / 6.0);
        else             v = 5.0 + (double)(i - 13) * (5.0 / 3.0);
        idx += (tv > (float)v) ? 1 : 0;
    }
    int slot = atomicAdd(&sc[idx], 1);
    rowlist[idx * B + slot] = b;
    __syncthreads();
    if (b < E) counts[b] = sc[b];
}

// ---------------------------------------------------------------------------
// Generic expert-gathered GEMM:
//   O[row, n0+n] = act( sum_k A[row,k] * W[e,k,n] (* mask) + bias[e,n] )
// rows gathered from rowlist[e*B + ...]; W row-major (K,N) per expert.
// act: 0=linear 1=relu 2=silu.  maskMode: 0 none, 1/2/3 = MADE M1/M2/M3.
// ---------------------------------------------------------------------------
__global__ __launch_bounds__(256) void gemm_expert(
    const float* __restrict__ A, int lda,
    const float* __restrict__ W, long long wsE,
    const float* __restrict__ bias, int bsE,
    float* __restrict__ O, int ldo,
    int K, int N,
    const int* __restrict__ rowlist, const int* __restrict__ counts,
    int act, int maskMode, int rev)
{
    int e = blockIdx.z;
    int cnt = counts[e];
    int r0 = blockIdx.y * TM;
    if (r0 >= cnt) return;
    int n0 = blockIdx.x * TN;
    int tid = threadIdx.x;

    __shared__ int rows_s[TM];
    if (tid < TM) {
        int r = r0 + tid;
        rows_s[tid] = (r < cnt) ? rowlist[e * B + r] : -1;
    }
    __shared__ float As[TK][TM];
    __shared__ float Bs[TK][TN];
    const float* We = W + (long long)e * wsE;

    float acc[4][4];
#pragma unroll
    for (int i = 0; i < 4; ++i)
#pragma unroll
        for (int j = 0; j < 4; ++j) acc[i][j] = 0.f;

    int am = tid >> 2;          // 0..63  : A row within tile
    int ak = (tid & 3) * 4;     // 0,4,8,12
    int bk = tid >> 4;          // 0..15  : B k within tile
    int bn = (tid & 15) * 4;    // 0..60
    int ty = tid >> 4;          // 0..15
    int tx = tid & 15;          // 0..15

    __syncthreads();            // rows_s ready

    for (int k0 = 0; k0 < K; k0 += TK) {
        int arow = rows_s[am];
#pragma unroll
        for (int j = 0; j < 4; ++j) {
            int k = k0 + ak + j;
            float v = 0.f;
            if (arow >= 0 && k < K) v = A[(long long)arow * lda + k];
            As[ak + j][am] = v;
        }
        {
            int kg = k0 + bk;
            const float* Wr = We + (long long)kg * N;
#pragma unroll
            for (int j = 0; j < 4; ++j) {
                int n = n0 + bn + j;
                float v = 0.f;
                if (kg < K && n < N) {
                    v = Wr[n];
                    if (maskMode) v *= made_mask(maskMode, rev, kg, n);
                }
                Bs[bk][bn + j] = v;
            }
        }
        __syncthreads();
#pragma unroll
        for (int kk = 0; kk < TK; ++kk) {
            float4 a  = *(const float4*)&As[kk][ty * 4];
            float4 b4 = *(const float4*)&Bs[kk][tx * 4];
            acc[0][0] += a.x * b4.x; acc[0][1] += a.x * b4.y; acc[0][2] += a.x * b4.z; acc[0][3] += a.x * b4.w;
            acc[1][0] += a.y * b4.x; acc[1][1] += a.y * b4.y; acc[1][2] += a.y * b4.z; acc[1][3] += a.y * b4.w;
            acc[2][0] += a.z * b4.x; acc[2][1] += a.z * b4.y; acc[2][2] += a.z * b4.z; acc[2][3] += a.z * b4.w;
            acc[3][0] += a.w * b4.x; acc[3][1] += a.w * b4.y; acc[3][2] += a.w * b4.z; acc[3][3] += a.w * b4.w;
        }
        __syncthreads();
    }

#pragma unroll
    for (int i = 0; i < 4; ++i) {
        int m = ty * 4 + i;
        int row = rows_s[m];
        if (row < 0) continue;
#pragma unroll
        for (int j = 0; j < 4; ++j) {
            int n = n0 + tx * 4 + j;
            if (n >= N) continue;
            float v = acc[i][j] + bias[e * bsE + n];
            if (act == 1) v = fmaxf(v, 0.f);
            else if (act == 2) v = v / (1.f + expf(-v));
            O[(long long)row * ldo + n] = v;
        }
    }
}

// ---------------------------------------------------------------------------
// small fused kernels
// ---------------------------------------------------------------------------
__global__ void build_xdat_kernel(const float* __restrict__ v_t,
                                  const float* __restrict__ t_prev,
                                  float* __restrict__ xdat) {
    long long i = (long long)blockIdx.x * blockDim.x + threadIdx.x;
    long long total = (long long)B * 1025;
    long long stride = (long long)gridDim.x * blockDim.x;
    for (; i < total; i += stride) {
        int b = (int)(i / 1025);
        int c = (int)(i % 1025);
        xdat[i] = (c < 1024) ? v_t[(long long)b * 1024 + c] : t_prev[b];
    }
}

__global__ void z_kernel(const float* __restrict__ phi, const float* __restrict__ eps,
                         float* __restrict__ inp, float* __restrict__ log_q,
                         float* __restrict__ ladj) {
    int b = blockIdx.x * blockDim.x + threadIdx.x;
    if (b >= B) return;
    float lq = 0.f;
#pragma unroll
    for (int f = 0; f < F; ++f) {
        float mu = phi[b * 32 + f];
        float ls = phi[b * 32 + 16 + f];
        float ep = eps[b * 16 + f];
        float z  = mu + expf(ls) * ep;
        inp[b * 272 + f] = z;
        lq += -0.5f * ep * ep - ls;
    }
    log_q[b] = lq - 16.f * 0.5f * LOG2PI;
    ladj[b] = 0.f;
}

__global__ __launch_bounds__(256) void logpx_kernel(const float* __restrict__ phid,
                                                    const float* __restrict__ xdat,
                                                    float* __restrict__ log_px) {
    int b = blockIdx.x;
    float s = 0.f;
    for (int i = threadIdx.x; i < DX; i += 256) {
        float mu = phid[(long long)b * 2050 + i];
        float ls = phid[(long long)b * 2050 + 1025 + i];
        float d  = (xdat[(long long)b * 1025 + i] - mu) * expf(-ls);
        s += -0.5f * d * d - ls;
    }
    for (int o = 32; o > 0; o >>= 1) s += __shfl_down(s, o, 64);
    __shared__ float sred[4];
    int w = threadIdx.x >> 6;
    if ((threadIdx.x & 63) == 0) sred[w] = s;
    __syncthreads();
    if (threadIdx.x == 0)
        log_px[b] = sred[0] + sred[1] + sred[2] + sred[3] - (float)DX * 0.5f * LOG2PI;
}

__global__ void made_update_kernel(const float* __restrict__ ph,
                                   float* __restrict__ inp,
                                   float* __restrict__ ladj) {
    int b = blockIdx.x * blockDim.x + threadIdx.x;
    if (b >= B) return;
    float la = ladj[b];
#pragma unroll
    for (int f = 0; f < F; ++f) {
        float sh = ph[b * 32 + f];
        float ls = ph[b * 32 + 16 + f];
        la += ls;
        float y = inp[b * 272 + f];
        inp[b * 272 + f] = y * expf(ls) + sh;
    }
    ladj[b] = la;
}

__global__ void final_kernel(const float* __restrict__ inp,
                             const float* __restrict__ log_px,
                             const float* __restrict__ log_q,
                             const float* __restrict__ ladj,
                             float* __restrict__ out) {
    int b = blockIdx.x * blockDim.x + threadIdx.x;
    if (b >= B) return;
    float s = 0.f;
#pragma unroll
    for (int f = 0; f < F; ++f) {
        float y = inp[b * 272 + f];
        s += -0.5f * y * y;
    }
    out[b] = log_px[b] + s - 16.f * 0.5f * LOG2PI + ladj[b] - log_q[b];
}

// ---------------------------------------------------------------------------
extern "C" void kernel_launch(void* const* d_in, const int* in_sizes, int n_in,
                              void* d_out, int out_size, void* d_ws, size_t ws_size,
                              hipStream_t stream) {
    const float* x_t    = (const float*)d_in[0];
    const float* v_t    = (const float*)d_in[1];
    const float* t      = (const float*)d_in[2];
    const float* t_prev = (const float*)d_in[3];
    const float* eps    = (const float*)d_in[4];
    const float* xW1 = (const float*)d_in[5];   const float* xb1 = (const float*)d_in[6];
    const float* xW2 = (const float*)d_in[7];   const float* xb2 = (const float*)d_in[8];
    const float* xW3 = (const float*)d_in[9];   const float* xb3 = (const float*)d_in[10];
    const float* tW1 = (const float*)d_in[11];  const float* tb1 = (const float*)d_in[12];
    const float* tW2 = (const float*)d_in[13];  const float* tb2 = (const float*)d_in[14];
    const float* tW3 = (const float*)d_in[15];  const float* tb3 = (const float*)d_in[16];
    const float* eW1 = (const float*)d_in[17];  const float* eb1 = (const float*)d_in[18];
    const float* eW2 = (const float*)d_in[19];  const float* eb2 = (const float*)d_in[20];
    const float* eW3 = (const float*)d_in[21];  const float* eb3 = (const float*)d_in[22];
    const float* dW1 = (const float*)d_in[23];  const float* db1 = (const float*)d_in[24];
    const float* dW2 = (const float*)d_in[25];  const float* db2 = (const float*)d_in[26];
    const float* dW3 = (const float*)d_in[27];  const float* db3 = (const float*)d_in[28];
    const float* mW1 = (const float*)d_in[29];  const float* mb1 = (const float*)d_in[30];
    const float* mW2 = (const float*)d_in[31];  const float* mb2 = (const float*)d_in[32];
    const float* mW3 = (const float*)d_in[33];  const float* mb3 = (const float*)d_in[34];

    // workspace layout
    int*   rowlist = (int*)d_ws;                 // E*B
    int*   counts  = rowlist + E * B;            // E (padded to 16)
    float* fbase   = (float*)(counts + 16);
    float* hA   = fbase;                         // B*1280
    float* hB   = hA  + (size_t)B * HC;          // B*1280
    float* ht1  = hB  + (size_t)B * HC;          // B*256
    float* ht2  = ht1 + (size_t)B * 256;         // B*256
    float* inp  = ht2 + (size_t)B * 256;         // B*272  [y | xe | te]
    float* xdat = inp + (size_t)B * 272;         // B*1025
    float* phi  = xdat + (size_t)B * 1025;       // B*32
    float* phid = phi + (size_t)B * 32;          // B*2050
    float* ph   = phid + (size_t)B * 2050;       // B*32
    float* log_q  = ph + (size_t)B * 32;         // B
    float* log_px = log_q + B;                   // B
    float* ladj   = log_px + B;                  // B

    prep_kernel<<<1, 1024, 0, stream>>>(t, rowlist, counts);

    auto G = [&](const float* A, int lda, const float* W, long long wsE,
                 const float* bias, int bsE, float* O, int ldo,
                 int K, int N, int act, int mask, int rev) {
        dim3 grid((N + TN - 1) / TN, B / TM, E);
        gemm_expert<<<grid, 256, 0, stream>>>(A, lda, W, wsE, bias, bsE, O, ldo,
                                              K, N, rowlist, counts, act, mask, rev);
    };

    // x-branch (silu), xe -> inp[:,16:144]
    G(x_t, 1024, xW1, 1024LL * HC, xb1, HC, hA, HC, 1024, HC, 2, 0, 0);
    G(hA, HC, xW2, (long long)HC * HC, xb2, HC, hB, HC, HC, HC, 2, 0, 0);
    G(hB, HC, xW3, (long long)HC * 128, xb3, 128, inp + 16, 272, HC, 128, 2, 0, 0);

    // t-branch (silu), te -> inp[:,144:272]
    G(t, 1, tW1, 256LL, tb1, 256, ht1, 256, 1, 256, 2, 0, 0);
    G(ht1, 256, tW2, 256LL * 256, tb2, 256, ht2, 256, 256, 256, 2, 0, 0);
    G(ht2, 256, tW3, 256LL * 128, tb3, 128, inp + 144, 272, 256, 128, 2, 0, 0);

    // xdat = [v_t | t_prev]
    build_xdat_kernel<<<1024, 256, 0, stream>>>(v_t, t_prev, xdat);

    // encoder (relu, relu, linear) -> phi
    G(xdat, 1025, eW1, 1025LL * HC, eb1, HC, hA, HC, 1025, HC, 1, 0, 0);
    G(hA, HC, eW2, (long long)HC * HC, eb2, HC, hB, HC, HC, HC, 1, 0, 0);
    G(hB, HC, eW3, (long long)HC * 32, eb3, 32, phi, 32, HC, 32, 0, 0, 0);

    // z, log_q ; z -> inp[:,0:16] ; ladj = 0
    z_kernel<<<4, 256, 0, stream>>>(phi, eps, inp, log_q, ladj);

    // decoder (relu, relu, linear) -> phid
    G(inp, 272, dW1, 16LL * HC, db1, HC, hA, HC, 16, HC, 1, 0, 0);
    G(hA, HC, dW2, (long long)HC * HC, db2, HC, hB, HC, HC, HC, 1, 0, 0);
    G(hB, HC, dW3, (long long)HC * 2050, db3, 2050, phid, 2050, HC, 2050, 0, 0, 0);

    logpx_kernel<<<B, 256, 0, stream>>>(phid, xdat, log_px);

    // MADE flow, 3 steps
    for (int k = 0; k < 3; ++k) {
        int rev = k & 1;
        G(inp, 272, mW1 + (size_t)k * 272 * 256, 3LL * 272 * 256,
          mb1 + (size_t)k * 256, 3 * 256, ht1, 256, 272, 256, 1, 1, rev);
        G(ht1, 256, mW2 + (size_t)k * 256 * 256, 3LL * 256 * 256,
          mb2 + (size_t)k * 256, 3 * 256, ht2, 256, 256, 256, 1, 2, rev);
        G(ht2, 256, mW3 + (size_t)k * 256 * 32, 3LL * 256 * 32,
          mb3 + (size_t)k * 32, 3 * 32, ph, 32, 256, 32, 0, 3, rev);
        made_update_kernel<<<4, 256, 0, stream>>>(ph, inp, ladj);
    }

    final_kernel<<<4, 256, 0, stream>>>(inp, log_px, log_q, ladj, (float*)d_out);
}